// Round 8
// baseline (13441.092 us; speedup 1.0000x reference)
//
#include <hip/hip_runtime.h>
#include <cstdint>
#include <cstddef>

// CayleyLinear: W = (I-A)^-1 (I+A), A = W0 - W0^T ; out = X W^T + bias
//   S = I + A A^T (SPD, eigs 1+sigma^2, ||S|| ~ 56)
//   Z ~= S^-1 via Newton-Schulz in the TRUE 3-factor form Z' = 2Z - Z S Z
//   W = 2 Z (I+A) - I ; out = X W^T + bias
//
// ROUND-8 ALGORITHM FIX (derived r7):
//  * r1/r4/r6 all used Z' = 2Z - Z Z S, whose residual map is
//    R' = R^2 + Z[dZ,S]S -- noise amplified by ||S||^2 ~ 3100. Explains all
//    three failures quantitatively (split: E~44; triple: E~1.3; fp32: E~1.5).
//  * True 3-factor form: T = Z S (exact via BT since S bitwise symmetric),
//    Z' = 2Z - Z T^T = 2Z - Z S Z given Z bitwise symmetric. R' = R^2 exact.
//  * Asymmetry of Z doubles each iteration (2Z term) -> bitwise symmetrize
//    Z every iteration (IEEE add commutativity => exact symmetry).
//  * Error model now E ~ |d1| + ||S||*|d2|: plain-fp32 floor ~0.014; last 2
//    iterations + S-build + W-step use Kahan accumulation -> floor ~1.5e-4.
// Scratch: ws 32 MiB (A, S/W). Za/Zb/T + vectors in d_out (all dead before
// the final GEMM rewrites d_out).

#define DIM 2048
#define POWER_STEPS 24
#define NEWTON_PLAIN 8
#define NEWTON_KAHAN 2

// ---------------------------------------------------------------------------
// fp32 BT-GEMM: C[m,n] = alpha * sum_k Aop[m,k]*Bop[n,k] + beta*D[m,n]
//               + gamma*(m==n) + bias[n]
// Aop, Bop row-major fp32, leading dim K. If bImA: Bop[n,k] := (n==k)-Bg[n,k].
// 64x64 tile, 256 threads, 4x4 per thread, BK=32, padded LDS.
// KAHAN: compensated accumulation -> only storage rounding remains.
// ---------------------------------------------------------------------------
template<bool KAHAN>
__global__ __launch_bounds__(256)
void gemm32_bt(const float* __restrict__ Ag, const float* __restrict__ Bg,
               float* __restrict__ Cg, const float* __restrict__ Dg,
               const float* __restrict__ biasg,
               int M, int N, int K,
               float alpha, float beta, float gamma, int bImA)
{
  __shared__ __align__(16) float As[64][34];
  __shared__ __align__(16) float Bs[64][34];

  const int nbn = N >> 6;
  const int bm = (int)blockIdx.x / nbn;
  const int bn = (int)blockIdx.x % nbn;
  const int m0 = bm << 6, n0 = bn << 6;

  const int t  = (int)threadIdx.x;   // 0..255
  const int tx = t & 15, ty = t >> 4;
  const int srow = t >> 2;           // 0..63
  const int scg  = (t & 3) << 3;     // 0,8,16,24

  float acc[4][4] = {};
  float cmp[4][4] = {};

  const size_t arow = (size_t)(m0 + srow) * (size_t)K;
  const size_t brow = (size_t)(n0 + srow) * (size_t)K;
  const int gn = n0 + srow;          // global B row (output col) for bImA

  for (int k0 = 0; k0 < K; k0 += 32) {
    {
      float4 v0 = *(const float4*)&Ag[arow + k0 + scg];
      float4 v1 = *(const float4*)&Ag[arow + k0 + scg + 4];
      As[srow][scg+0] = v0.x; As[srow][scg+1] = v0.y;
      As[srow][scg+2] = v0.z; As[srow][scg+3] = v0.w;
      As[srow][scg+4] = v1.x; As[srow][scg+5] = v1.y;
      As[srow][scg+6] = v1.z; As[srow][scg+7] = v1.w;
    }
    {
      float4 v0 = *(const float4*)&Bg[brow + k0 + scg];
      float4 v1 = *(const float4*)&Bg[brow + k0 + scg + 4];
      float vv[8] = {v0.x, v0.y, v0.z, v0.w, v1.x, v1.y, v1.z, v1.w};
      if (bImA) {
        #pragma unroll
        for (int i = 0; i < 8; ++i) {
          int gk = k0 + scg + i;
          vv[i] = ((gn == gk) ? 1.0f : 0.0f) - vv[i];
        }
      }
      #pragma unroll
      for (int i = 0; i < 8; ++i) Bs[srow][scg + i] = vv[i];
    }
    __syncthreads();

    #pragma unroll
    for (int kk = 0; kk < 32; kk += 2) {
      float2 a2[4], b2[4];
      #pragma unroll
      for (int i = 0; i < 4; ++i)
        a2[i] = *(const float2*)&As[(ty << 2) + i][kk];
      #pragma unroll
      for (int i = 0; i < 4; ++i)
        b2[i] = *(const float2*)&Bs[(tx << 2) + i][kk];
      #pragma unroll
      for (int i = 0; i < 4; ++i)
        #pragma unroll
        for (int j = 0; j < 4; ++j) {
          if constexpr (KAHAN) {
            float y = __builtin_fmaf(a2[i].x, b2[j].x, -cmp[i][j]);
            float s = acc[i][j] + y;
            cmp[i][j] = (s - acc[i][j]) - y;
            acc[i][j] = s;
            y = __builtin_fmaf(a2[i].y, b2[j].y, -cmp[i][j]);
            s = acc[i][j] + y;
            cmp[i][j] = (s - acc[i][j]) - y;
            acc[i][j] = s;
          } else {
            acc[i][j] = __builtin_fmaf(a2[i].x, b2[j].x, acc[i][j]);
            acc[i][j] = __builtin_fmaf(a2[i].y, b2[j].y, acc[i][j]);
          }
        }
    }
    __syncthreads();
  }

  #pragma unroll
  for (int i = 0; i < 4; ++i) {
    const int row = m0 + (ty << 2) + i;
    #pragma unroll
    for (int j = 0; j < 4; ++j) {
      const int col = n0 + (tx << 2) + j;
      float v = alpha * acc[i][j];
      if (Dg) v += beta * Dg[(size_t)row * (size_t)N + col];
      if (gamma != 0.0f && row == col) v += gamma;
      if (biasg) v += biasg[col];
      Cg[(size_t)row * (size_t)N + col] = v;
    }
  }
}

// ---------------------------------------------------------------------------
// bitwise symmetrize: out = (in + in^T)/2. Tile-pair blocks, LDS transpose.
// out[i][j] and out[j][i] compute 0.5f*(a+b) vs 0.5f*(b+a): bitwise equal.
// ---------------------------------------------------------------------------
__global__ __launch_bounds__(256) void sym_k(const float* __restrict__ in,
                                             float* __restrict__ outp)
{
  int p = (int)blockIdx.x;           // triangular pair index, T=64 tiles
  int bi = 0, a = 0;
  while (a + (64 - bi) <= p) { a += 64 - bi; ++bi; }
  int bj = bi + (p - a);

  __shared__ float T1[32][33];
  __shared__ float T2[32][33];
  const int c = (int)threadIdx.x & 31, r0 = ((int)threadIdx.x >> 5) << 2;

  #pragma unroll
  for (int rr = 0; rr < 4; ++rr) {
    int r = r0 + rr;
    T1[r][c] = in[(size_t)(bi * 32 + r) * DIM + bj * 32 + c];
    T2[r][c] = in[(size_t)(bj * 32 + r) * DIM + bi * 32 + c];
  }
  __syncthreads();
  #pragma unroll
  for (int rr = 0; rr < 4; ++rr) {
    int r = r0 + rr;
    outp[(size_t)(bi * 32 + r) * DIM + bj * 32 + c] = 0.5f * (T1[r][c] + T2[c][r]);
    if (bi != bj)
      outp[(size_t)(bj * 32 + r) * DIM + bi * 32 + c] = 0.5f * (T2[r][c] + T1[c][r]);
  }
}

// ---------------------------------------------------------------------------
// small kernels
// ---------------------------------------------------------------------------
__global__ __launch_bounds__(256) void skew_k(const float* __restrict__ W0,
                                              float* __restrict__ A)
{
  int idx = (int)blockIdx.x * 256 + (int)threadIdx.x;
  int i = idx >> 11, j = idx & 2047;
  A[idx] = W0[(size_t)i * DIM + j] - W0[(size_t)j * DIM + i];
}

__global__ __launch_bounds__(256) void initv_k(float* __restrict__ v)
{
  int idx = (int)blockIdx.x * 256 + (int)threadIdx.x;
  uint32_t h = (uint32_t)idx * 2654435761u;
  v[idx] = 0.5f + (float)(h >> 8) * (1.0f / 16777216.0f);   // [0.5, 1.5)
}

__global__ __launch_bounds__(256) void matvec_k(const float* __restrict__ A,
                                                const float* __restrict__ x,
                                                float* __restrict__ y,
                                                float scale)
{
  const int row = (int)blockIdx.x;
  const int t = (int)threadIdx.x;
  const float* ar = A + (size_t)row * DIM;
  float s = 0.f;
  for (int j = t; j < DIM; j += 256) s += ar[j] * x[j];
  #pragma unroll
  for (int off = 32; off; off >>= 1) s += __shfl_down(s, off);
  __shared__ float red[4];
  if ((t & 63) == 0) red[t >> 6] = s;
  __syncthreads();
  if (t == 0) y[row] = scale * (red[0] + red[1] + red[2] + red[3]);
}

// rho = ||t||^2/||v||^2 (Rayleigh, <= sigma_max^2). Chebyshev(1) warm-start
// coefs for 1/s over [1, B], B = 1 + 1.6*rho; e0 ~ 0.91.
__global__ __launch_bounds__(256) void rayleigh_k(const float* __restrict__ tvec,
                                                  const float* __restrict__ vvec,
                                                  float* __restrict__ coefs)
{
  const int t = (int)threadIdx.x;
  float s1 = 0.f, s2 = 0.f;
  for (int j = t; j < DIM; j += 256) {
    float a = tvec[j]; s1 += a * a;
    float b = vvec[j]; s2 += b * b;
  }
  #pragma unroll
  for (int off = 32; off; off >>= 1) {
    s1 += __shfl_down(s1, off);
    s2 += __shfl_down(s2, off);
  }
  __shared__ float r1[4], r2[4];
  if ((t & 63) == 0) { r1[t >> 6] = s1; r2[t >> 6] = s2; }
  __syncthreads();
  if (t == 0) {
    float n1 = r1[0] + r1[1] + r1[2] + r1[3];
    float n2 = r2[0] + r2[1] + r2[2] + r2[3];
    float rho = n1 / n2;
    float B   = 1.0f + 1.6f * rho;
    float Sg = B + 1.0f, Dl = B - 1.0f;
    float den = 2.0f * Sg * Sg - Dl * Dl;
    coefs[0] = 8.0f * Sg / den;          // Z0 = c0*I + c1*S
    coefs[1] = -8.0f / den;
  }
}

__global__ __launch_bounds__(256) void z0_k(const float* __restrict__ S,
                                            const float* __restrict__ coefs,
                                            float* __restrict__ Z)
{
  const float c0 = coefs[0], c1 = coefs[1];
  int idx = (int)blockIdx.x * 256 + (int)threadIdx.x;
  int i = idx >> 11, j = idx & 2047;
  Z[idx] = c1 * S[idx] + ((i == j) ? c0 : 0.0f);
}

// ---------------------------------------------------------------------------
extern "C" void kernel_launch(void* const* d_in, const int* in_sizes, int n_in,
                              void* d_out, int out_size, void* d_ws, size_t ws_size,
                              hipStream_t stream)
{
  const float* X    = (const float*)d_in[0];   // (8192, 2048)
  const float* W0   = (const float*)d_in[1];   // (2048, 2048)
  const float* bias = (const float*)d_in[2];   // (2048,)
  float* out = (float*)d_out;                  // (8192, 2048) = 64 MiB

  const size_t MB16 = (size_t)DIM * DIM * sizeof(float);   // 16 MiB
  char* ws = (char*)d_ws;
  char* ob = (char*)d_out;
  float* Abuf = (float*)(ws + 0 * MB16);
  float* Sbuf = (float*)(ws + 1 * MB16);   // S during Newton; W afterwards
  float* Wbuf = Sbuf;
  float* Za   = (float*)(ob + 0 * MB16);   // Zc: current (symmetric) iterate
  float* Zb   = (float*)(ob + 1 * MB16);   // Zn: raw update
  float* Tb   = (float*)(ob + 2 * MB16);   // T = Z*S
  float* vec  = (float*)(ob + 3 * MB16);   // power-iter vectors (dead later)
  float* va = vec, * vb = vec + 4096, * tv = vec + 8192, * coefs = vec + 12288;

  const dim3 b256(256);
  const float* FN = nullptr;
  const dim3 gSq((DIM / 64) * (DIM / 64));        // 1024 blocks
  const dim3 gOut((8192 / 64) * (DIM / 64));      // 4096 blocks
  const dim3 gSym(64 * 65 / 2);                   // 2080 tile-pairs

  // A = W0 - W0^T
  hipLaunchKernelGGL(skew_k, dim3((DIM * DIM) / 256), b256, 0, stream, W0, Abuf);

  // power iteration on A^T A (= -A^2): sigma_max^2 Rayleigh estimate
  hipLaunchKernelGGL(initv_k, dim3(DIM / 256), b256, 0, stream, va);
  float* vc = va; float* vo = vb;
  for (int i = 0; i < POWER_STEPS; ++i) {
    hipLaunchKernelGGL(matvec_k, dim3(DIM), b256, 0, stream, Abuf, vc, tv, 1.0f);
    hipLaunchKernelGGL(matvec_k, dim3(DIM), b256, 0, stream, Abuf, tv, vo, -1.0f / 16.0f);
    float* tmp = vc; vc = vo; vo = tmp;
  }
  hipLaunchKernelGGL(matvec_k, dim3(DIM), b256, 0, stream, Abuf, vc, tv, 1.0f);
  hipLaunchKernelGGL(rayleigh_k, dim3(1), b256, 0, stream, tv, vc, coefs);

  // S = I + A A^T   (Kahan; bitwise symmetric by construction)
  hipLaunchKernelGGL((gemm32_bt<true>), gSq, b256, 0, stream,
                     Abuf, Abuf, Sbuf, FN, FN,
                     DIM, DIM, DIM, 1.0f, 0.0f, 1.0f, 0);

  // Z0 = c0 I + c1 S  (bitwise symmetric since S is)
  hipLaunchKernelGGL(z0_k, dim3((DIM * DIM) / 256), b256, 0, stream, Sbuf, coefs, Za);

  // Newton-Schulz, 3-factor form with per-iteration symmetrization:
  //   T  = BT(Z, S)  = Z S          (exact: S bitwise symmetric)
  //   Zn = 2Z - BT(Z, T) = 2Z - Z S Z   (exact 3-factor: Z bitwise symmetric)
  //   Z  = sym(Zn)                  (kill asymmetry doubling)
  for (int it = 0; it < NEWTON_PLAIN + NEWTON_KAHAN; ++it) {
    if (it < NEWTON_PLAIN) {
      hipLaunchKernelGGL((gemm32_bt<false>), gSq, b256, 0, stream,
                         Za, Sbuf, Tb, FN, FN, DIM, DIM, DIM, 1.0f, 0.0f, 0.0f, 0);
      hipLaunchKernelGGL((gemm32_bt<false>), gSq, b256, 0, stream,
                         Za, Tb, Zb, Za, FN, DIM, DIM, DIM, -1.0f, 2.0f, 0.0f, 0);
    } else {
      hipLaunchKernelGGL((gemm32_bt<true>), gSq, b256, 0, stream,
                         Za, Sbuf, Tb, FN, FN, DIM, DIM, DIM, 1.0f, 0.0f, 0.0f, 0);
      hipLaunchKernelGGL((gemm32_bt<true>), gSq, b256, 0, stream,
                         Za, Tb, Zb, Za, FN, DIM, DIM, DIM, -1.0f, 2.0f, 0.0f, 0);
    }
    hipLaunchKernelGGL(sym_k, gSym, b256, 0, stream, Zb, Za);
  }

  // W = 2 Z (I+A) - I = 2 * BT(Z, I-A) - I   (Kahan; into Sbuf slot, S dead)
  hipLaunchKernelGGL((gemm32_bt<true>), gSq, b256, 0, stream,
                     Za, Abuf, Wbuf, FN, FN,
                     DIM, DIM, DIM, 2.0f, 0.0f, -1.0f, 1);

  // out = X W^T + bias   (plain fp32; fully rewrites d_out)
  hipLaunchKernelGGL((gemm32_bt<false>), gOut, b256, 0, stream,
                     X, Wbuf, out, FN, bias,
                     8192, DIM, DIM, 1.0f, 0.0f, 0.0f, 0);
}